// Round 8
// baseline (183.661 us; speedup 1.0000x reference)
//
#include <hip/hip_runtime.h>
#include <math.h>

#define BB 8
#define TT 1024
#define SS 77

typedef short v8s __attribute__((ext_vector_type(8)));
typedef float v4f __attribute__((ext_vector_type(4)));
typedef unsigned short u16x4 __attribute__((ext_vector_type(4)));
typedef unsigned short u16x8 __attribute__((ext_vector_type(8)));
typedef unsigned short u16;

// fold 64^-0.25 * sqrt(log2 e) into q and k weights -> logits in exp2-domain
#define SCALEF 0.424660891f
#define MASKNEG (-14426.95f)   // -10000 * log2(e)

__device__ __forceinline__ u16 f2bf(float f) {
  unsigned u = __float_as_uint(f);
  u = (u + 0x7fffu + ((u >> 16) & 1u)) >> 16;
  return (u16)u;
}
__device__ __forceinline__ u16 hi16(float f) {
  return (u16)(__float_as_uint(f) >> 16);
}
__device__ __forceinline__ float bf2f(u16 u) {
  return __uint_as_float(((unsigned)u) << 16);
}
__device__ __forceinline__ void gl_lds16(const void* g, void* l) {
  __builtin_amdgcn_global_load_lds(
      (const __attribute__((address_space(1))) void*)g,
      (__attribute__((address_space(3))) void*)l, 16, 0, 0);
}

// ---------------------------------------------------------------------------
// Fused GroupNorm (blocks 0..255) + prep (blocks 256..2304).
// ---------------------------------------------------------------------------
__global__ __launch_bounds__(256) void prep_gn_kernel(
    const float* __restrict__ x, const float* __restrict__ scale,
    const float* __restrict__ bias, u16* __restrict__ nrmT,
    const float* __restrict__ qkv_w, const float* __restrict__ ekv_w,
    const float* __restrict__ proj_w, const float* __restrict__ enc,
    const float* __restrict__ qkv_b, const float* __restrict__ ekv_b,
    u16* __restrict__ wQK, u16* __restrict__ wV, u16* __restrict__ wEK,
    u16* __restrict__ wEV, u16* __restrict__ projwb, u16* __restrict__ encT,
    float* __restrict__ bQK, float* __restrict__ bV,
    float* __restrict__ bEK, float* __restrict__ bEV) {
  __shared__ u16 Xs[16 * 1024];
  __shared__ float red[8];
  int blk = blockIdx.x, tid = threadIdx.x;

  if (blk < 256) {             // ---- GroupNorm path ----
    int bg = blk;
    int b = bg >> 5, g = bg & 31;
    const float4* x4 = (const float4*)(x + (size_t)bg * 16384);
    float s = 0.f, sq = 0.f;
#pragma unroll
    for (int i = 0; i < 16; ++i) {
      int idx = tid + 256 * i;
      float4 v = x4[idx];
      s += v.x + v.y + v.z + v.w;
      sq += v.x * v.x + v.y * v.y + v.z * v.z + v.w * v.w;
      int c = idx >> 8, t4 = (idx & 255) * 4;
      u16x4 o; o.x = f2bf(v.x); o.y = f2bf(v.y); o.z = f2bf(v.z); o.w = f2bf(v.w);
      *(u16x4*)(Xs + c * 1024 + t4) = o;
    }
#pragma unroll
    for (int off = 32; off > 0; off >>= 1) {
      s += __shfl_down(s, off, 64);
      sq += __shfl_down(sq, off, 64);
    }
    int wave = tid >> 6;
    if ((tid & 63) == 0) { red[wave] = s; red[wave + 4] = sq; }
    __syncthreads();
    float ts = red[0] + red[1] + red[2] + red[3];
    float tq = red[4] + red[5] + red[6] + red[7];
    float mu = ts * (1.0f / 16384.0f);
    float var = tq * (1.0f / 16384.0f) - mu * mu;
    float rs = rsqrtf(var + 1e-5f);
    float scv[16], biv[16];
#pragma unroll
    for (int c = 0; c < 16; ++c) {
      float ss = scale[g * 16 + c] * rs;
      scv[c] = ss;
      biv[c] = bias[g * 16 + c] - mu * ss;
    }
#pragma unroll
    for (int j = 0; j < 4; ++j) {
      int t = tid + 256 * j;
      u16x8 o0, o1;
#pragma unroll
      for (int c = 0; c < 8; ++c)  o0[c] = f2bf(bf2f(Xs[c * 1024 + t]) * scv[c] + biv[c]);
#pragma unroll
      for (int c = 8; c < 16; ++c) o1[c - 8] = f2bf(bf2f(Xs[c * 1024 + t]) * scv[c] + biv[c]);
      u16* dst = nrmT + ((size_t)b * 1024 + t) * 512 + g * 16;
      *(u16x8*)dst = o0;
      *(u16x8*)(dst + 8) = o1;
    }
    return;
  }

  int p = blk - 256;           // ---- prep path ----
  if (p < 512) {               // wQK (scaled)
    int idx = p * 256 + tid;
    int n = idx >> 7, c4 = (idx & 127) * 4;
    int which = n >> 9, h = (n >> 6) & 7, ch = n & 63;
    int src = h * 192 + which * 64 + ch;
    float4 v = *(const float4*)(qkv_w + (size_t)src * 512 + c4);
    u16x4 o; o.x = f2bf(v.x * SCALEF); o.y = f2bf(v.y * SCALEF);
    o.z = f2bf(v.z * SCALEF); o.w = f2bf(v.w * SCALEF);
    *(u16x4*)(wQK + (size_t)n * 512 + c4) = o;
  } else if (p < 768) {        // wV
    int idx = (p - 512) * 256 + tid;
    int n = idx >> 7, c4 = (idx & 127) * 4;
    int h = n >> 6, ch = n & 63;
    int src = h * 192 + 128 + ch;
    float4 v = *(const float4*)(qkv_w + (size_t)src * 512 + c4);
    u16x4 o; o.x = f2bf(v.x); o.y = f2bf(v.y); o.z = f2bf(v.z); o.w = f2bf(v.w);
    *(u16x4*)(wV + (size_t)n * 512 + c4) = o;
  } else if (p < 1024) {       // wEK (scaled)
    int idx = (p - 768) * 256 + tid;
    int n = idx >> 7, c4 = (idx & 127) * 4;
    int h = n >> 6, ch = n & 63;
    int src = h * 128 + ch;
    float4 v = *(const float4*)(ekv_w + (size_t)src * 512 + c4);
    u16x4 o; o.x = f2bf(v.x * SCALEF); o.y = f2bf(v.y * SCALEF);
    o.z = f2bf(v.z * SCALEF); o.w = f2bf(v.w * SCALEF);
    *(u16x4*)(wEK + (size_t)n * 512 + c4) = o;
  } else if (p < 1280) {       // wEV
    int idx = (p - 1024) * 256 + tid;
    int n = idx >> 7, c4 = (idx & 127) * 4;
    int h = n >> 6, ch = n & 63;
    int src = h * 128 + 64 + ch;
    float4 v = *(const float4*)(ekv_w + (size_t)src * 512 + c4);
    u16x4 o; o.x = f2bf(v.x); o.y = f2bf(v.y); o.z = f2bf(v.z); o.w = f2bf(v.w);
    *(u16x4*)(wEV + (size_t)n * 512 + c4) = o;
  } else if (p < 1536) {       // projwb
    int idx = (p - 1280) * 256 + tid;
    float4 v = ((const float4*)proj_w)[idx];
    u16x4 o; o.x = f2bf(v.x); o.y = f2bf(v.y); o.z = f2bf(v.z); o.w = f2bf(v.w);
    *(u16x4*)(projwb + (size_t)idx * 4) = o;
  } else if (p < 2048) {       // encT [b][128][512], zero-padded
    int idx = (p - 1536) * 256 + tid;
    int b = idx >> 14, rem = idx & 16383;
    int s = rem >> 7, c = (rem & 127) * 4;
    u16x4 o; o.x = 0; o.y = 0; o.z = 0; o.w = 0;
    if (s < SS) {
      const float* pp = enc + ((size_t)b * 512 + c) * SS + s;
      o.x = f2bf(pp[0]); o.y = f2bf(pp[SS]); o.z = f2bf(pp[2 * SS]); o.w = f2bf(pp[3 * SS]);
    }
    *(u16x4*)(encT + ((size_t)b * 128 + s) * 512 + c) = o;
  } else {                     // biases (permuted; q/k scaled)
    for (int i = tid; i < 2560; i += 256) {
      if (i < 1024) {
        int which = i >> 9, h = (i >> 6) & 7, ch = i & 63;
        bQK[i] = qkv_b[h * 192 + which * 64 + ch] * SCALEF;
      } else if (i < 1536) {
        int j = i - 1024; int h = j >> 6, ch = j & 63;
        bV[j] = qkv_b[h * 192 + 128 + ch];
      } else if (i < 2048) {
        int j = i - 1536; int h = j >> 6, ch = j & 63;
        bEK[j] = ekv_b[h * 128 + ch] * SCALEF;
      } else {
        int j = i - 2048; int h = j >> 6, ch = j & 63;
        bEV[j] = ekv_b[h * 128 + 64 + ch];
      }
    }
  }
}

// ---------------------------------------------------------------------------
// Unified projection GEMM: all four projections (QK, EK, V, EV) in ONE
// launch. grid = (104 jobs, 8 batches). 128x128 tile, BK=64, m97 staging.
// ---------------------------------------------------------------------------
__global__ __launch_bounds__(256) void proj_all(
    const u16* __restrict__ nrmT, const u16* __restrict__ encT,
    const u16* __restrict__ wQK, const u16* __restrict__ wEK,
    const u16* __restrict__ wV, const u16* __restrict__ wEV,
    const float* __restrict__ bQK, const float* __restrict__ bEK,
    const float* __restrict__ bV, const float* __restrict__ bEV,
    u16* __restrict__ Qh, u16* __restrict__ Kfull, u16* __restrict__ Vfull) {
  __shared__ __align__(16) u16 SH[16384];
  u16* As = SH;
  u16* Bs = SH + 8192;

  int job = blockIdx.x, bz = blockIdx.y;
  int tid = threadIdx.x;
  int lane = tid & 63, w = tid >> 6;
  int lan15 = lane & 15, quad = lane >> 4;
  int wm = w >> 1, wn = w & 1;

  int mode, m0, n0;
  const u16 *Ap, *Bp;
  const float* bias;
  u16 *dA = nullptr, *dB = nullptr;
  int TrA = 0, offA = 0, TrB = 0, offB = 0;
  int coff = 0;

  if (job < 64) {
    mode = 3; m0 = (job >> 3) * 128; n0 = (job & 7) * 128;
    Ap = nrmT + (size_t)bz * 1024 * 512; Bp = wQK; bias = bQK;
    dA = Qh; TrA = 1024; offA = 0; dB = Kfull; TrB = 1152; offB = 128;
  } else if (job < 68) {
    mode = 3; m0 = 0; n0 = (job - 64) * 128;
    Ap = encT + (size_t)bz * 128 * 512; Bp = wEK; bias = bEK;
    dA = Kfull; TrA = 1152; offA = 0; dB = Kfull; TrB = 1152; offB = 0;
  } else if (job < 100) {
    int jj = job - 68; mode = 0; m0 = (jj >> 3) * 128; n0 = (jj & 7) * 128;
    Ap = wV; Bp = nrmT + (size_t)bz * 1024 * 512; bias = bV;
    coff = 128;
  } else {
    int jj = job - 100; mode = 0; m0 = jj * 128; n0 = 0;
    Ap = wEV; Bp = encT + (size_t)bz * 128 * 512; bias = bEV;
    coff = 0;
  }

  int srow = lane >> 3;
  int schunk = (lane & 7) ^ srow;
  const char* Ag = (const char*)(Ap + (size_t)(m0 + w * 32 + srow) * 512) + schunk * 16;
  const char* Bg = (const char*)(Bp + (size_t)(n0 + w * 32 + srow) * 512) + schunk * 16;
  char* Al = (char*)As + w * 4096;
  char* Bl = (char*)Bs + w * 4096;

  v4f acc[4][4] = {};

  for (int step = 0; step < 8; ++step) {
    __syncthreads();
    int kb = step * 128;
#pragma unroll
    for (int i = 0; i < 4; ++i) gl_lds16(Ag + kb + i * 8192, Al + i * 1024);
#pragma unroll
    for (int i = 0; i < 4; ++i) gl_lds16(Bg + kb + i * 8192, Bl + i * 1024);
    __syncthreads();

#pragma unroll
    for (int ksub = 0; ksub < 2; ++ksub) {
      int ch = ((ksub * 4 + quad) ^ (lan15 & 7)) * 16;
      v8s a[4], bf[4];
#pragma unroll
      for (int i = 0; i < 4; ++i)
        a[i] = *(const v8s*)((const char*)As + (wm * 64 + i * 16 + lan15) * 128 + ch);
#pragma unroll
      for (int j = 0; j < 4; ++j)
        bf[j] = *(const v8s*)((const char*)Bs + (wn * 64 + j * 16 + lan15) * 128 + ch);
#pragma unroll
      for (int i = 0; i < 4; ++i)
#pragma unroll
        for (int j = 0; j < 4; ++j)
          acc[i][j] = __builtin_amdgcn_mfma_f32_16x16x32_bf16(a[i], bf[j], acc[i][j], 0, 0, 0);
    }
  }

  if (mode == 3) {
    u16* Tr = SH;              // [128][72]
    for (int ph = 0; ph < 2; ++ph) {
      __syncthreads();
      if (wn == ph) {
#pragma unroll
        for (int j = 0; j < 4; ++j) {
          int n = n0 + wn * 64 + j * 16 + lan15;
          float bv_ = bias[n];
#pragma unroll
          for (int i = 0; i < 4; ++i)
#pragma unroll
            for (int r = 0; r < 4; ++r)
              Tr[(wm * 64 + i * 16 + quad * 4 + r) * 72 + j * 16 + lan15] =
                  f2bf(acc[i][j][r] + bv_);
        }
      }
      __syncthreads();
      int nb = n0 + ph * 64;
      u16* dst = (nb < 512) ? dA : dB;
      int Trows = (nb < 512) ? TrA : TrB;
      int roff  = (nb < 512) ? offA : offB;
      int hh = (nb & 511) >> 6;
      int row = tid >> 1, seg = (tid & 1) * 32;
      u16* dp = dst + ((size_t)(bz * 8 + hh) * Trows + roff + m0 + row) * 64 + seg;
#pragma unroll
      for (int g = 0; g < 4; ++g)
        *(u16x8*)(dp + g * 8) = *(const u16x8*)(Tr + row * 72 + seg + g * 8);
    }
  } else {
    u16* Tr = SH;              // [128 m][72] per phase of 64 n
    u16* Cb = Vfull + (size_t)bz * 512 * 1152;
    for (int ph = 0; ph < 2; ++ph) {
      __syncthreads();
      if (wn == ph) {
#pragma unroll
        for (int i = 0; i < 4; ++i) {
          int ob = wm * 64 + i * 16 + quad * 4;
#pragma unroll
          for (int r = 0; r < 4; ++r) {
            float bi = bias[m0 + ob + r];
#pragma unroll
            for (int j = 0; j < 4; ++j)
              Tr[(ob + r) * 72 + j * 16 + lan15] = f2bf(acc[i][j][r] + bi);
          }
        }
      }
      __syncthreads();
      int row = tid >> 1, seg = (tid & 1) * 32;
      u16* dp = Cb + (size_t)(m0 + row) * 1152 + coff + n0 + ph * 64 + seg;
#pragma unroll
      for (int g = 0; g < 4; ++g)
        *(u16x8*)(dp + g * 8) = *(const u16x8*)(Tr + row * 72 + seg + g * 8);
    }
  }
}

// ---------------------------------------------------------------------------
// proj-out GEMM: out = x + proj_w @ attn.
// ---------------------------------------------------------------------------
__global__ __launch_bounds__(256) void proj_out(
    const u16* __restrict__ A, const u16* __restrict__ B,
    const float* __restrict__ bias, const float* __restrict__ res,
    float* __restrict__ Cf) {
  __shared__ __align__(16) u16 SH[16384];
  u16* As = SH;
  u16* Bs = SH + 8192;

  int tid = threadIdx.x;
  int lane = tid & 63, w = tid >> 6;
  int lan15 = lane & 15, quad = lane >> 4;
  int wm = w >> 1, wn = w & 1;
  int m0 = blockIdx.y * 128, n0 = blockIdx.x * 128;
  int bz = blockIdx.z;
  const u16* Bb = B + (size_t)bz * 1024 * 512;

  int srow = lane >> 3;
  int schunk = (lane & 7) ^ srow;
  const char* Ag = (const char*)(A + (size_t)(m0 + w * 32 + srow) * 512) + schunk * 16;
  const char* Bg = (const char*)(Bb + (size_t)(n0 + w * 32 + srow) * 512) + schunk * 16;
  char* Al = (char*)As + w * 4096;
  char* Bl = (char*)Bs + w * 4096;

  v4f acc[4][4] = {};

  for (int step = 0; step < 8; ++step) {
    __syncthreads();
    int kb = step * 128;
#pragma unroll
    for (int i = 0; i < 4; ++i) gl_lds16(Ag + kb + i * 8192, Al + i * 1024);
#pragma unroll
    for (int i = 0; i < 4; ++i) gl_lds16(Bg + kb + i * 8192, Bl + i * 1024);
    __syncthreads();

#pragma unroll
    for (int ksub = 0; ksub < 2; ++ksub) {
      int ch = ((ksub * 4 + quad) ^ (lan15 & 7)) * 16;
      v8s a[4], bf[4];
#pragma unroll
      for (int i = 0; i < 4; ++i)
        a[i] = *(const v8s*)((const char*)As + (wm * 64 + i * 16 + lan15) * 128 + ch);
#pragma unroll
      for (int j = 0; j < 4; ++j)
        bf[j] = *(const v8s*)((const char*)Bs + (wn * 64 + j * 16 + lan15) * 128 + ch);
#pragma unroll
      for (int i = 0; i < 4; ++i)
#pragma unroll
        for (int j = 0; j < 4; ++j)
          acc[i][j] = __builtin_amdgcn_mfma_f32_16x16x32_bf16(a[i], bf[j], acc[i][j], 0, 0, 0);
    }
  }

  const float* rb = res + (size_t)bz * 512 * 1024;
  float* Cb = Cf + (size_t)bz * 512 * 1024;
#pragma unroll
  for (int i = 0; i < 4; ++i) {
    int ob = m0 + wm * 64 + i * 16 + quad * 4;
#pragma unroll
    for (int r = 0; r < 4; ++r) {
      int o = ob + r;
      float bi = bias[o];
#pragma unroll
      for (int j = 0; j < 4; ++j) {
        int n = n0 + wn * 64 + j * 16 + lan15;
        Cb[(size_t)o * 1024 + n] = acc[i][j][r] + bi + rb[(size_t)o * 1024 + n];
      }
    }
  }
}

// ---------------------------------------------------------------------------
// MFMA flash attention v5: wave owns 64 t (mt=4), block = 2 waves = 128 t.
// S^T-form QK (packed b64 P stores) + O^T-form PV (direct global store
// epilogue, per-lane l with no LDS transpose). K/V double-buffered,
// 1 barrier/chunk. grid (64 bh, 8 t-tiles).
// ---------------------------------------------------------------------------
#define AOFF_K 0           // 2 x 8192
#define AOFF_V 16384       // 2 x 8192
#define AOFF_P 32768       // 2 waves x 9216 (Q overlay + P [64 t][72 s])
#define AOFF_AM 51200      // 128 f32 mask
#define ASMEM  51712

__global__ __launch_bounds__(128, 2) void attn_kernel(
    const u16* __restrict__ Qh, const u16* __restrict__ Kf,
    const u16* __restrict__ Vf, const int* __restrict__ mask,
    u16* __restrict__ attnT) {
  __shared__ __align__(16) unsigned char smem[ASMEM];
  float* AM = (float*)(smem + AOFF_AM);

  int bh = blockIdx.x, b = bh >> 3, h = bh & 7;
  int t0 = blockIdx.y * 128;
  int tid = threadIdx.x;              // 0..127
  int lane = tid & 63, w = tid >> 6;  // w in {0,1}
  int lan15 = lane & 15, quad = lane >> 4;
  int r8 = lane >> 3, c8 = lane & 7;
  int swE = (c8 ^ r8) * 8;

  const u16* Qb = Qh + (size_t)bh * 1024 * 64;
  const u16* Kb = Kf + (size_t)bh * 1152 * 64;
  const u16* Vb = Vf + (size_t)bh * 64 * 1152;
  char* Pw = (char*)smem + AOFF_P + w * 9216;   // wave-private Q/P region
  u16* Pu = (u16*)Pw;

  AM[tid] = (tid < SS) ? ((mask[h * SS + tid] != 0) ? 0.f : MASKNEG) : -1e30f;

  // stage Q (64 t x 64 ch per wave, into private region) + chunk 0 K/V
#pragma unroll
  for (int i = 0; i < 8; ++i)
    gl_lds16(Qb + (size_t)(t0 + w * 64 + i * 8 + r8) * 64 + swE, Pw + i * 1024);
#pragma unroll
  for (int i = 0; i < 4; ++i) {
    int row = w * 32 + i * 8;
    gl_lds16(Kb + (size_t)(row + r8) * 64 + swE, (char*)smem + AOFF_K + row * 128);
    gl_lds16(Vb + (size_t)(row + r8) * 1152 + swE, (char*)smem + AOFF_V + row * 128);
  }
  __syncthreads();

  // hoist Q fragments (MFMA B-operand: B[k=ch][n=t], t = mt*16 + lan15)
  v8s aq[4][2];
#pragma unroll
  for (int mt = 0; mt < 4; ++mt)
#pragma unroll
    for (int ks = 0; ks < 2; ++ks)
      aq[mt][ks] = *(const v8s*)(Pw + (mt * 16 + lan15) * 128 +
                                 (((ks * 4 + quad) ^ (lan15 & 7)) * 16));

  v4f O[4][4] = {};        // O^T[nc][mt]: col=t(lan15), row=c(quad*4+r)
  float lsum[4] = {};      // per-lane, t = mt*16 + lan15

  for (int c = 0; c < 18; ++c) {
    int cur = c & 1;
    if (c < 17) {
      int nb = cur ^ 1;
#pragma unroll
      for (int i = 0; i < 4; ++i) {
        int row = w * 32 + i * 8;
        gl_lds16(Kb + (size_t)((c + 1) * 64 + row + r8) * 64 + swE,
                 (char*)smem + AOFF_K + nb * 8192 + row * 128);
        gl_lds16(Vb + (size_t)(row + r8) * 1152 + (c + 1) * 64 + swE,
                 (char*)smem + AOFF_V + nb * 8192 + row * 128);
      }
    }
    const char* Kc = (const char*)smem + AOFF_K + cur * 8192;
    const char* Vc = (const char*)smem + AOFF_V + cur * 8192;

    // QK^T transposed: ST[nt][mt], row = s (quad*4+r), col = t (lan15)
    v4f ST[4][4] = {};
#pragma unroll
    for (int ks = 0; ks < 2; ++ks) {
      int cofs = ((ks * 4 + quad) ^ (lan15 & 7)) * 16;
      v8s bk[4];
#pragma unroll
      for (int nt = 0; nt < 4; ++nt)
        bk[nt] = *(const v8s*)(Kc + (nt * 16 + lan15) * 128 + cofs);
#pragma unroll
      for (int nt = 0; nt < 4; ++nt)
#pragma unroll
        for (int mt = 0; mt < 4; ++mt)
          ST[nt][mt] = __builtin_amdgcn_mfma_f32_16x16x32_bf16(bk[nt], aq[mt][ks], ST[nt][mt], 0, 0, 0);
    }

    // mask add (enc chunks only): s = c*64 + nt*16 + quad*4 + r
    if (c < 2) {
#pragma unroll
      for (int nt = 0; nt < 4; ++nt)
#pragma unroll
        for (int r = 0; r < 4; ++r) {
          float a_ = AM[c * 64 + nt * 16 + quad * 4 + r];
#pragma unroll
          for (int mt = 0; mt < 4; ++mt) ST[nt][mt][r] += a_;
        }
    }

    // exp2 + b64-packed P store: Pu[t*72 + nt*16 + quad*4] = {e0..e3}
#pragma unroll
    for (int mt = 0; mt < 4; ++mt) {
#pragma unroll
      for (int nt = 0; nt < 4; ++nt) {
        float e0 = __builtin_amdgcn_exp2f(ST[nt][mt][0]);
        float e1 = __builtin_amdgcn_exp2f(ST[nt][mt][1]);
        float e2 = __builtin_amdgcn_exp2f(ST[nt][mt][2]);
        float e3 = __builtin_amdgcn_exp2f(ST[nt][mt][3]);
        u16x4 pk; pk.x = hi16(e0); pk.y = hi16(e1); pk.z = hi16(e2); pk.w = hi16(e3);
        *(u16x4*)&Pu[(mt * 16 + lan15) * 72 + nt * 16 + quad * 4] = pk;
        lsum[mt] += (e0 + e1) + (e2 + e3);
      }
    }

    // PV in O^T form: O^T[nc][mt] += mfma(A=bv[nc], B=ap[mt])
#pragma unroll
    for (int ks = 0; ks < 2; ++ks) {
      int cofs = ((ks * 4 + quad) ^ (lan15 & 7)) * 16;
      v8s ap[4], bv[4];
#pragma unroll
      for (int mt = 0; mt < 4; ++mt)
        ap[mt] = *(const v8s*)(Pw + (mt * 16 + lan15) * 144 + ks * 64 + quad * 16);
#pragma unroll
      for (int nc = 0; nc < 4; ++nc)
        bv[nc] = *(const v8s*)(Vc + (nc * 16 + lan15) * 128 + cofs);
#pragma unroll
      for (int nc = 0; nc < 4; ++nc)
#pragma unroll
        for (int mt = 0; mt < 4; ++mt)
          O[nc][mt] = __builtin_amdgcn_mfma_f32_16x16x32_bf16(bv[nc], ap[mt], O[nc][mt], 0, 0, 0);
    }
    __syncthreads();
  }

  // l: cross-quad reduce (t = mt*16+lan15, replicated across quads)
  float inv[4];
#pragma unroll
  for (int mt = 0; mt < 4; ++mt) {
    float v = lsum[mt];
    v += __shfl_xor(v, 16, 64);
    v += __shfl_xor(v, 32, 64);
    inv[mt] = 1.0f / v;
  }

  // epilogue: direct packed global stores — lane's 4 acc values are
  // c-contiguous (c = nc*16 + quad*4 + r) at fixed t = t0 + w*64 + mt*16 + lan15
#pragma unroll
  for (int mt = 0; mt < 4; ++mt) {
    int t = t0 + w * 64 + mt * 16 + lan15;
    u16* dp = attnT + ((size_t)b * 1024 + t) * 512 + h * 64 + quad * 4;
#pragma unroll
    for (int nc = 0; nc < 4; ++nc) {
      u16x4 pk;
      pk.x = f2bf(O[nc][mt][0] * inv[mt]);
      pk.y = f2bf(O[nc][mt][1] * inv[mt]);
      pk.z = f2bf(O[nc][mt][2] * inv[mt]);
      pk.w = f2bf(O[nc][mt][3] * inv[mt]);
      *(u16x4*)(dp + nc * 16) = pk;
    }
  }
}

// ---------------------------------------------------------------------------
extern "C" void kernel_launch(void* const* d_in, const int* in_sizes, int n_in,
                              void* d_out, int out_size, void* d_ws, size_t ws_size,
                              hipStream_t stream) {
  const float* x       = (const float*)d_in[0];
  const float* enc     = (const float*)d_in[1];
  const int*   mask    = (const int*)d_in[2];
  const float* nscale  = (const float*)d_in[3];
  const float* nbias   = (const float*)d_in[4];
  const float* qkv_w   = (const float*)d_in[5];
  const float* qkv_b   = (const float*)d_in[6];
  const float* ekv_w   = (const float*)d_in[7];
  const float* ekv_b   = (const float*)d_in[8];
  const float* proj_w  = (const float*)d_in[9];
  const float* proj_b  = (const float*)d_in[10];
  float* out = (float*)d_out;

  char* ws = (char*)d_ws;
  const size_t MiB = 1048576;
  u16* nrmT   = (u16*)(ws);                        // 8 MiB  [8][1024][512]
  u16* Qh     = (u16*)(ws + 8 * MiB);              // 8 MiB  [64][1024][64]
  u16* Kfull  = (u16*)(ws + 16 * MiB);             // 9.4 MiB [64][1152][64]
  u16* Vfull  = (u16*)(ws + 26 * MiB);             // 9.4 MiB [64][64][1152]
  u16* attnT  = (u16*)(ws + 36 * MiB);             // 8 MiB  [8][1024][512]
  u16* encT   = (u16*)(ws + 44 * MiB);             // 1 MiB  [8][128][512]
  u16* wQK    = (u16*)(ws + 45 * MiB);             // 1 MiB
  u16* wV     = (u16*)(ws + 46 * MiB);             // 0.5 MiB
  u16* wEK    = (u16*)(ws + 46 * MiB + 524288);
  u16* wEV    = (u16*)(ws + 47 * MiB);
  u16* projwb = (u16*)(ws + 47 * MiB + 524288);
  float* bQK  = (float*)(ws + 48 * MiB);
  float* bV   = (float*)(ws + 48 * MiB + 4096);
  float* bEK  = (float*)(ws + 48 * MiB + 6144);
  float* bEV  = (float*)(ws + 48 * MiB + 8192);

  // 1) fused GroupNorm + prep
  prep_gn_kernel<<<dim3(2305), dim3(256), 0, stream>>>(
      x, nscale, nbias, nrmT, qkv_w, ekv_w, proj_w, enc, qkv_b, ekv_b,
      wQK, wV, wEK, wEV, projwb, encT, bQK, bV, bEK, bEV);

  // 2) ALL projections (QK + EK + V + EV) in one launch
  proj_all<<<dim3(104, BB), dim3(256), 0, stream>>>(
      nrmT, encT, wQK, wEK, wV, wEV, bQK, bEK, bV, bEV, Qh, Kfull, Vfull);

  // 3) attention -> attnT [8][1024][512]  (2-wave blocks, 64 t per wave)
  attn_kernel<<<dim3(64, 8), dim3(128), 0, stream>>>(
      Qh, Kfull, Vfull, mask, attnT);

  // 4) out = x + proj_w @ attn
  proj_out<<<dim3(8, 4, BB), dim3(256), 0, stream>>>(
      projwb, attnT, proj_b, x, out);
}